// Round 5
// baseline (454.542 us; speedup 1.0000x reference)
//
#include <hip/hip_runtime.h>
#include <math.h>

// Problem constants (fixed by reference): B=16, L=8, A_CH=2, H=W=384, HID=64
#define HWDIM 384
#define PPX   (HWDIM * HWDIM)   // 147456 px per image
#define NBL   128               // B*L
#define NB    16
#define NPART 576               // 144 blocks * 4 waves per image

// ws layout (floats):
//   [1024,   +73728)   partA (conf partials,    128 * 576)
//   [74752,  +73728)   partO (overlap partials, 128 * 576)
//   [148480, +9216)    partD (demand partials,   16 * 576)
#define PART_A_OFF  1024
#define PART_O_OFF  74752
#define PART_D_OFF  148480

__device__ __forceinline__ float fast_sigmoid(float x) {
    return 1.0f / (1.0f + __expf(-x));
}

// force a block-uniform float into an SGPR
__device__ __forceinline__ float uload(const float* p) {
    union { float f; int i; } u;
    u.f = *p;
    u.i = __builtin_amdgcn_readfirstlane(u.i);
    return u.f;
}

// conf at integer source loc, recomputed from psm (sigmoid(max(ch0,ch1)))
__device__ __forceinline__ float conf_sample(const float* __restrict__ img0,
                                             int yi, int xi) {
    bool valid = ((unsigned)xi < HWDIM) && ((unsigned)yi < HWDIM);
    int yc = min(max(yi, 0), HWDIM - 1);
    int xc = min(max(xi, 0), HWDIM - 1);
    int off = yc * HWDIM + xc;
    return valid ? fast_sigmoid(fmaxf(img0[off], img0[off + PPX])) : 0.0f;
}

// ---- Fused single pass over psm: conf-mean + warp-overlap + demand ---------
// 1D grid 18432 = 128 img * 144 blk, XCD-swizzled: image's blocks on ONE XCD,
// consecutive in time -> gather window stays L2-resident. 4 px/thread.
__global__ __launch_bounds__(256) void heavy_kernel(
    const float* __restrict__ psm, const float* __restrict__ req,
    const float* __restrict__ naff, float* __restrict__ ws)
{
    // swizzle: flat%8 = XCD (dispatch round-robin heuristic; perf-only)
    const int flat = blockIdx.x;
    const int xcd  = flat & 7;
    const int s    = flat >> 3;           // 0..2303
    const int img_in_xcd = s / 144;       // 0..15 (sequential per XCD)
    const int blk  = s - img_in_xcd * 144;// 0..143
    const int bl   = (xcd << 4) | img_in_xcd;
    const int b = bl >> 3;
    const int l = bl & 7;
    const int t = threadIdx.x;

    const float* img0   = psm + (size_t)bl * (2 * PPX);
    const float* di_img = req + (size_t)(b * 8) * PPX;

    const int ab = (b * 64 + l) * 6;      // norm_affine[b,0,l]
    const float a00 = uload(naff + ab + 0), a01 = uload(naff + ab + 1);
    const float a02 = uload(naff + ab + 2), a10 = uload(naff + ab + 3);
    const float a11 = uload(naff + ab + 4), a12 = uload(naff + ab + 5);

    const int p0 = blk * 1024 + t * 4;
    const float step  = 2.0f / (float)(HWDIM - 1);
    const float half_ = 0.5f * (float)(HWDIM - 1);
    const int y = p0 / HWDIM;             // 4 px share a row (384 % 4 == 0)
    const int x = p0 - y * HWDIM;
    const float gyv = fmaf((float)y, step, -1.0f);

    float4 c0  = *(const float4*)(img0 + p0);
    float4 c1  = *(const float4*)(img0 + PPX + p0);
    float4 di4 = *(const float4*)(di_img + p0);

    float s_conf = 0.0f, s_ov = 0.0f;
    float s_di = (di4.x + di4.y) + (di4.z + di4.w);

    #pragma unroll
    for (int j = 0; j < 4; ++j) {
        s_conf += fast_sigmoid(fmaxf((&c0.x)[j], (&c1.x)[j]));

        const float gxv = fmaf((float)(x + j), step, -1.0f);
        float sx = a00 * gxv + a01 * gyv + a02;
        float sy = a10 * gxv + a11 * gyv + a12;
        float pxf = (sx + 1.0f) * half_;
        float pyf = (sy + 1.0f) * half_;
        float x0f = floorf(pxf), y0f = floorf(pyf);
        float wx = pxf - x0f, wy = pyf - y0f;
        int x0 = (int)x0f, y0 = (int)y0f;
        float v00 = conf_sample(img0, y0,     x0);
        float v01 = conf_sample(img0, y0,     x0 + 1);
        float v10 = conf_sample(img0, y0 + 1, x0);
        float v11 = conf_sample(img0, y0 + 1, x0 + 1);
        float top = v00 + wx * (v01 - v00);
        float bot = v10 + wx * (v11 - v10);
        s_ov = fmaf((&di4.x)[j], top + wy * (bot - top), s_ov);
    }

    for (int o = 32; o > 0; o >>= 1) {
        s_conf += __shfl_down(s_conf, o);
        s_ov   += __shfl_down(s_ov,   o);
        s_di   += __shfl_down(s_di,   o);
    }
    if ((t & 63) == 0) {
        const int pi = blk * 4 + (t >> 6);
        ws[PART_A_OFF + bl * NPART + pi] = s_conf;
        ws[PART_O_OFF + bl * NPART + pi] = s_ov;
        if (l == 0) ws[PART_D_OFF + b * NPART + pi] = s_di;
    }
}

// ---- MLP head, one wave per (b,l); reduces its own partials inline ---------
__global__ __launch_bounds__(64) void mlp_kernel(
    const float* __restrict__ ws, const float* __restrict__ naff,
    const float* __restrict__ qW1, const float* __restrict__ qb1,
    const float* __restrict__ qW2, const float* __restrict__ qb2,
    const float* __restrict__ kW1, const float* __restrict__ kb1,
    const float* __restrict__ kW2, const float* __restrict__ kb2,
    const float* __restrict__ eW1, const float* __restrict__ eb1,
    const float* __restrict__ eW2, const float* __restrict__ eb2,
    float* __restrict__ out)
{
    const int bl = blockIdx.x;
    const int b = bl >> 3;
    const int l = bl & 7;
    const int t = threadIdx.x;
    const float invP = 1.0f / (float)PPX;

    // reduce the 4 needed partial arrays (576 each), butterfly -> all lanes
    const float* pa  = ws + PART_A_OFF + bl * NPART;
    const float* pa0 = ws + PART_A_OFF + (b * 8) * NPART;
    const float* po  = ws + PART_O_OFF + bl * NPART;
    const float* pd  = ws + PART_D_OFF + b * NPART;
    float sA = 0.0f, sA0 = 0.0f, sO = 0.0f, sD = 0.0f;
    for (int k = t; k < NPART; k += 64) {
        sA += pa[k]; sA0 += pa0[k]; sO += po[k]; sD += pd[k];
    }
    for (int o = 32; o > 0; o >>= 1) {
        sA  += __shfl_xor(sA,  o);
        sA0 += __shfl_xor(sA0, o);
        sO  += __shfl_xor(sO,  o);
        sD  += __shfl_xor(sD,  o);
    }

    const float demand = sD * invP;
    const float mc0    = sA0 * invP;
    const float mc     = sA * invP;
    const float ov     = sO * invP;

    const int abase = (b * 64 + l) * 6;
    const float dx = naff[abase + 2];
    const float dy = naff[abase + 5];
    const float dist = sqrtf(dx * dx + dy * dy);

    const int dbase  = (b * 64 + 9 * l) * 6;   // norm_affine[b,l,l]
    const int dbase0 = (b * 64) * 6;           // norm_affine[b,0,0]
    const float yawl = atan2f(naff[dbase + 3],  naff[dbase + 0]);
    const float yaw0 = atan2f(naff[dbase0 + 3], naff[dbase0 + 0]);
    const float tt = yaw0 - yawl;       // cos/sin(atan2(sin t,cos t))==cos/sin(t)
    const float cosd = cosf(tt), sind = sinf(tt);

    const float ego[8] = {mc0, demand, 0.0f, 0.0f, 1.0f, 0.0f, 0.0f, demand};
    const float fj[8]  = {mc, ov, dx, dy, cosd, sind, dist, demand};

    __shared__ float sh[64];
    __shared__ float qv[64];
    __shared__ float kv[64];

    float h = qb1[t];
    for (int i = 0; i < 8; ++i) h = fmaf(ego[i], qW1[i * 64 + t], h);
    sh[t] = fmaxf(h, 0.0f);
    __syncthreads();
    float q2 = qb2[t];
    for (int i = 0; i < 64; ++i) q2 = fmaf(sh[i], qW2[i * 64 + t], q2);
    qv[t] = q2;
    __syncthreads();

    float hk = kb1[t];
    for (int i = 0; i < 8; ++i) hk = fmaf(fj[i], kW1[i * 64 + t], hk);
    sh[t] = fmaxf(hk, 0.0f);
    __syncthreads();
    float k2 = kb2[t];
    for (int i = 0; i < 64; ++i) k2 = fmaf(sh[i], kW2[i * 64 + t], k2);
    kv[t] = k2;
    __syncthreads();

    float he = eb1[t];
    for (int i = 0; i < 64; ++i) he = fmaf(qv[i], eW1[i * 64 + t], he);
    for (int i = 0; i < 64; ++i) he = fmaf(kv[i], eW1[(64 + i) * 64 + t], he);
    he = fmaxf(he, 0.0f);

    float part = he * eW2[t];
    for (int o = 32; o > 0; o >>= 1) part += __shfl_down(part, o);

    if (t == 0) {
        float r;
        if (l == 0) {
            r = 0.0f;                   // logits[:,0] = -1e9 -> sigmoid -> 0
        } else {
            float logit = part + eb2[0];
            r = 1.0f / (1.0f + expf(-logit));
            r = fminf(fmaxf(r, 0.0f), 1.0f);
        }
        out[bl] = r;
    }
}

extern "C" void kernel_launch(void* const* d_in, const int* in_sizes, int n_in,
                              void* d_out, int out_size, void* d_ws, size_t ws_size,
                              hipStream_t stream) {
    const float* psm  = (const float*)d_in[0];
    const float* req  = (const float*)d_in[1];
    const float* naff = (const float*)d_in[2];
    const float* qW1 = (const float*)d_in[4];
    const float* qb1 = (const float*)d_in[5];
    const float* qW2 = (const float*)d_in[6];
    const float* qb2 = (const float*)d_in[7];
    const float* kW1 = (const float*)d_in[8];
    const float* kb1 = (const float*)d_in[9];
    const float* kW2 = (const float*)d_in[10];
    const float* kb2 = (const float*)d_in[11];
    const float* eW1 = (const float*)d_in[12];
    const float* eb1 = (const float*)d_in[13];
    const float* eW2 = (const float*)d_in[14];
    const float* eb2 = (const float*)d_in[15];
    float* out = (float*)d_out;
    float* ws  = (float*)d_ws;

    hipLaunchKernelGGL(heavy_kernel, dim3(144 * NBL), dim3(256), 0, stream,
                       psm, req, naff, ws);
    hipLaunchKernelGGL(mlp_kernel, dim3(NBL), dim3(64), 0, stream,
                       ws, naff,
                       qW1, qb1, qW2, qb2, kW1, kb1, kW2, kb2,
                       eW1, eb1, eW2, eb2, out);
}

// Round 6
// 308.603 us; speedup vs baseline: 1.4729x; 1.4729x over previous
//
#include <hip/hip_runtime.h>
#include <hip/hip_fp16.h>
#include <math.h>

// Problem constants (fixed by reference): B=16, L=8, A_CH=2, H=W=384, HID=64
#define HWDIM 384
#define PPX   (HWDIM * HWDIM)   // 147456 px per image
#define NBL   128               // B*L
#define NB    16
#define NPART 576               // 144 blocks * 4 waves per image

// ws layout (floats):
//   [1024,   +73728)   partA (conf partials,    128 * 576)
//   [74752,  +73728)   partO (overlap partials, 128 * 576)
//   [148480, +9216)    partD (demand partials,   16 * 576)
// byte 1048576: conf PAIR cache, __half2 per px = (conf[x], conf[x+1]); 75.5 MB
#define PART_A_OFF  1024
#define PART_O_OFF  74752
#define PART_D_OFF  148480
#define PAIR_OFF_B  1048576
#define PAIR_BYTES  ((size_t)NBL * PPX * 4)

__device__ __forceinline__ float fast_sigmoid(float x) {
    return 1.0f / (1.0f + __expf(-x));
}

// force a block-uniform float into an SGPR
__device__ __forceinline__ float uload(const float* p) {
    union { float f; int i; } u;
    u.f = *p;
    u.i = __builtin_amdgcn_readfirstlane(u.i);
    return u.f;
}

// ---- Pass 1: conf = sigmoid(max(ch0,ch1)) -> half2 PAIR cache + partials ---
// grid (144, 128), 256 thr, 4 px/thread (float4 streams). Pair (c[x], c[x+1]).
__global__ __launch_bounds__(256) void conf_kernel(
    const float* __restrict__ psm, __half2* __restrict__ pairs,
    float* __restrict__ ws)
{
    const int bl = blockIdx.y;
    const int t  = threadIdx.x;
    const float* img0 = psm + (size_t)bl * (2 * PPX);
    const int p0 = blockIdx.x * 1024 + t * 4;

    float4 c0 = *(const float4*)(img0 + p0);
    float4 c1 = *(const float4*)(img0 + PPX + p0);

    float v0 = fast_sigmoid(fmaxf(c0.x, c1.x));
    float v1 = fast_sigmoid(fmaxf(c0.y, c1.y));
    float v2 = fast_sigmoid(fmaxf(c0.z, c1.z));
    float v3 = fast_sigmoid(fmaxf(c0.w, c1.w));

    // neighbor conf (px p0+4) = next lane's v0; lane 63 recomputes directly
    const int lane = t & 63;
    float vn = __shfl(v0, (lane + 1) & 63);
    if (lane == 63) {
        const int pn = p0 + 4;
        float a = 0.0f;
        if (pn < PPX) a = fast_sigmoid(fmaxf(img0[pn], img0[pn + PPX]));
        vn = a;  // value only consumed when x<383, junk masked at gather time
    }

    union { __half2 h[4]; uint4 u; } pk;
    pk.h[0] = __floats2half2_rn(v0, v1);
    pk.h[1] = __floats2half2_rn(v1, v2);
    pk.h[2] = __floats2half2_rn(v2, v3);
    pk.h[3] = __floats2half2_rn(v3, vn);
    *(uint4*)(pairs + (size_t)bl * PPX + p0) = pk.u;

    float s = (v0 + v1) + (v2 + v3);
    for (int o = 32; o > 0; o >>= 1) s += __shfl_down(s, o);
    if (lane == 0)
        ws[PART_A_OFF + bl * NPART + blockIdx.x * 4 + (t >> 6)] = s;
}

// ---- Pass 2: warp-overlap + demand. Wave-contiguous px mapping. ------------
// 1D grid 18432 = 128 img * 144 blk, XCD-swizzled (image -> one XCD).
__global__ __launch_bounds__(256) void overlap_kernel(
    const float* __restrict__ req, const float* __restrict__ naff,
    const __half2* __restrict__ pairs, float* __restrict__ ws)
{
    const int flat = blockIdx.x;
    const int xcd  = flat & 7;
    const int s    = flat >> 3;            // 0..2303
    const int img_in_xcd = s / 144;        // 0..15
    const int blk  = s - img_in_xcd * 144; // 0..143
    const int bl   = (xcd << 4) | img_in_xcd;
    const int b = bl >> 3;
    const int l = bl & 7;
    const int t = threadIdx.x;

    const float* di_img = req + (size_t)(b * 8) * PPX;
    const __half2* pimg = pairs + (size_t)bl * PPX;

    const int ab = (b * 64 + l) * 6;       // norm_affine[b,0,l]
    const float a00 = uload(naff + ab + 0), a01 = uload(naff + ab + 1);
    const float a02 = uload(naff + ab + 2), a10 = uload(naff + ab + 3);
    const float a11 = uload(naff + ab + 4), a12 = uload(naff + ab + 5);

    const float step  = 2.0f / (float)(HWDIM - 1);
    const float half_ = 0.5f * (float)(HWDIM - 1);

    float acc = 0.0f, sdi = 0.0f;

    #pragma unroll
    for (int j = 0; j < 4; ++j) {
        const int p = blk * 1024 + j * 256 + t;   // lane-consecutive px
        const float di = di_img[p];
        sdi += di;

        const int y = p / HWDIM;
        const int x = p - y * HWDIM;
        const float gxv = fmaf((float)x, step, -1.0f);
        const float gyv = fmaf((float)y, step, -1.0f);
        float sx = a00 * gxv + a01 * gyv + a02;
        float sy = a10 * gxv + a11 * gyv + a12;
        float pxf = (sx + 1.0f) * half_;
        float pyf = (sy + 1.0f) * half_;
        float x0f = floorf(pxf), y0f = floorf(pyf);
        float wx = pxf - x0f, wy = pyf - y0f;
        int x0 = (int)x0f, y0 = (int)y0f;

        const bool vx0 = (unsigned)x0 < (unsigned)HWDIM;
        const bool vx1 = (unsigned)(x0 + 1) < (unsigned)HWDIM;
        const bool vy0 = (unsigned)y0 < (unsigned)HWDIM;
        const bool vy1 = (unsigned)(y0 + 1) < (unsigned)HWDIM;
        const int xc  = min(max(x0, 0), HWDIM - 1);
        const int yc0 = min(max(y0, 0), HWDIM - 1);
        const int yc1 = min(max(y0 + 1, 0), HWDIM - 1);

        float2 r0 = __half22float2(pimg[yc0 * HWDIM + xc]);
        float2 r1 = __half22float2(pimg[yc1 * HWDIM + xc]);

        // pair = (conf[xc], conf[xc+1]); handle x0==-1 shift + masking
        float v00, v01, v10, v11;
        if (vx0) {
            v00 = r0.x; v01 = vx1 ? r0.y : 0.0f;
            v10 = r1.x; v11 = vx1 ? r1.y : 0.0f;
        } else {
            v00 = 0.0f; v01 = vx1 ? r0.x : 0.0f;
            v10 = 0.0f; v11 = vx1 ? r1.x : 0.0f;
        }
        if (!vy0) { v00 = 0.0f; v01 = 0.0f; }
        if (!vy1) { v10 = 0.0f; v11 = 0.0f; }

        float top = v00 + wx * (v01 - v00);
        float bot = v10 + wx * (v11 - v10);
        acc = fmaf(di, top + wy * (bot - top), acc);
    }

    for (int o = 32; o > 0; o >>= 1) {
        acc += __shfl_down(acc, o);
        sdi += __shfl_down(sdi, o);
    }
    if ((t & 63) == 0) {
        const int pi = blk * 4 + (t >> 6);
        ws[PART_O_OFF + bl * NPART + pi] = acc;
        if (l == 0) ws[PART_D_OFF + b * NPART + pi] = sdi;
    }
}

// ---- Fallback fused single pass (if ws too small for pair cache) -----------
__device__ __forceinline__ float conf_sample(const float* __restrict__ img0,
                                             int yi, int xi) {
    bool valid = ((unsigned)xi < HWDIM) && ((unsigned)yi < HWDIM);
    int yc = min(max(yi, 0), HWDIM - 1);
    int xc = min(max(xi, 0), HWDIM - 1);
    int off = yc * HWDIM + xc;
    return valid ? fast_sigmoid(fmaxf(img0[off], img0[off + PPX])) : 0.0f;
}

__global__ __launch_bounds__(256) void heavy_kernel(
    const float* __restrict__ psm, const float* __restrict__ req,
    const float* __restrict__ naff, float* __restrict__ ws)
{
    const int flat = blockIdx.x;
    const int xcd  = flat & 7;
    const int s    = flat >> 3;
    const int img_in_xcd = s / 144;
    const int blk  = s - img_in_xcd * 144;
    const int bl   = (xcd << 4) | img_in_xcd;
    const int b = bl >> 3;
    const int l = bl & 7;
    const int t = threadIdx.x;

    const float* img0   = psm + (size_t)bl * (2 * PPX);
    const float* di_img = req + (size_t)(b * 8) * PPX;
    const int ab = (b * 64 + l) * 6;
    const float a00 = uload(naff + ab + 0), a01 = uload(naff + ab + 1);
    const float a02 = uload(naff + ab + 2), a10 = uload(naff + ab + 3);
    const float a11 = uload(naff + ab + 4), a12 = uload(naff + ab + 5);

    const int p0 = blk * 1024 + t * 4;
    const float step  = 2.0f / (float)(HWDIM - 1);
    const float half_ = 0.5f * (float)(HWDIM - 1);
    const int y = p0 / HWDIM;
    const int x = p0 - y * HWDIM;
    const float gyv = fmaf((float)y, step, -1.0f);

    float4 c0  = *(const float4*)(img0 + p0);
    float4 c1  = *(const float4*)(img0 + PPX + p0);
    float4 di4 = *(const float4*)(di_img + p0);

    float s_conf = 0.0f, s_ov = 0.0f;
    float s_di = (di4.x + di4.y) + (di4.z + di4.w);

    #pragma unroll
    for (int j = 0; j < 4; ++j) {
        s_conf += fast_sigmoid(fmaxf((&c0.x)[j], (&c1.x)[j]));
        const float gxv = fmaf((float)(x + j), step, -1.0f);
        float sx = a00 * gxv + a01 * gyv + a02;
        float sy = a10 * gxv + a11 * gyv + a12;
        float pxf = (sx + 1.0f) * half_;
        float pyf = (sy + 1.0f) * half_;
        float x0f = floorf(pxf), y0f = floorf(pyf);
        float wx = pxf - x0f, wy = pyf - y0f;
        int x0 = (int)x0f, y0 = (int)y0f;
        float v00 = conf_sample(img0, y0,     x0);
        float v01 = conf_sample(img0, y0,     x0 + 1);
        float v10 = conf_sample(img0, y0 + 1, x0);
        float v11 = conf_sample(img0, y0 + 1, x0 + 1);
        float top = v00 + wx * (v01 - v00);
        float bot = v10 + wx * (v11 - v10);
        s_ov = fmaf((&di4.x)[j], top + wy * (bot - top), s_ov);
    }

    for (int o = 32; o > 0; o >>= 1) {
        s_conf += __shfl_down(s_conf, o);
        s_ov   += __shfl_down(s_ov,   o);
        s_di   += __shfl_down(s_di,   o);
    }
    if ((t & 63) == 0) {
        const int pi = blk * 4 + (t >> 6);
        ws[PART_A_OFF + bl * NPART + pi] = s_conf;
        ws[PART_O_OFF + bl * NPART + pi] = s_ov;
        if (l == 0) ws[PART_D_OFF + b * NPART + pi] = s_di;
    }
}

// ---- MLP head, one wave per (b,l); reduces its own partials inline ---------
__global__ __launch_bounds__(64) void mlp_kernel(
    const float* __restrict__ ws, const float* __restrict__ naff,
    const float* __restrict__ qW1, const float* __restrict__ qb1,
    const float* __restrict__ qW2, const float* __restrict__ qb2,
    const float* __restrict__ kW1, const float* __restrict__ kb1,
    const float* __restrict__ kW2, const float* __restrict__ kb2,
    const float* __restrict__ eW1, const float* __restrict__ eb1,
    const float* __restrict__ eW2, const float* __restrict__ eb2,
    float* __restrict__ out)
{
    const int bl = blockIdx.x;
    const int b = bl >> 3;
    const int l = bl & 7;
    const int t = threadIdx.x;
    const float invP = 1.0f / (float)PPX;

    const float* pa  = ws + PART_A_OFF + bl * NPART;
    const float* pa0 = ws + PART_A_OFF + (b * 8) * NPART;
    const float* po  = ws + PART_O_OFF + bl * NPART;
    const float* pd  = ws + PART_D_OFF + b * NPART;
    float sA = 0.0f, sA0 = 0.0f, sO = 0.0f, sD = 0.0f;
    for (int k = t; k < NPART; k += 64) {
        sA += pa[k]; sA0 += pa0[k]; sO += po[k]; sD += pd[k];
    }
    for (int o = 32; o > 0; o >>= 1) {
        sA  += __shfl_xor(sA,  o);
        sA0 += __shfl_xor(sA0, o);
        sO  += __shfl_xor(sO,  o);
        sD  += __shfl_xor(sD,  o);
    }

    const float demand = sD * invP;
    const float mc0    = sA0 * invP;
    const float mc     = sA * invP;
    const float ov     = sO * invP;

    const int abase = (b * 64 + l) * 6;
    const float dx = naff[abase + 2];
    const float dy = naff[abase + 5];
    const float dist = sqrtf(dx * dx + dy * dy);

    const int dbase  = (b * 64 + 9 * l) * 6;   // norm_affine[b,l,l]
    const int dbase0 = (b * 64) * 6;           // norm_affine[b,0,0]
    const float yawl = atan2f(naff[dbase + 3],  naff[dbase + 0]);
    const float yaw0 = atan2f(naff[dbase0 + 3], naff[dbase0 + 0]);
    const float tt = yaw0 - yawl;       // cos/sin(atan2(sin t,cos t))==cos/sin(t)
    const float cosd = cosf(tt), sind = sinf(tt);

    const float ego[8] = {mc0, demand, 0.0f, 0.0f, 1.0f, 0.0f, 0.0f, demand};
    const float fj[8]  = {mc, ov, dx, dy, cosd, sind, dist, demand};

    __shared__ float sh[64];
    __shared__ float qv[64];
    __shared__ float kv[64];

    float h = qb1[t];
    for (int i = 0; i < 8; ++i) h = fmaf(ego[i], qW1[i * 64 + t], h);
    sh[t] = fmaxf(h, 0.0f);
    __syncthreads();
    float q2 = qb2[t];
    for (int i = 0; i < 64; ++i) q2 = fmaf(sh[i], qW2[i * 64 + t], q2);
    qv[t] = q2;
    __syncthreads();

    float hk = kb1[t];
    for (int i = 0; i < 8; ++i) hk = fmaf(fj[i], kW1[i * 64 + t], hk);
    sh[t] = fmaxf(hk, 0.0f);
    __syncthreads();
    float k2 = kb2[t];
    for (int i = 0; i < 64; ++i) k2 = fmaf(sh[i], kW2[i * 64 + t], k2);
    kv[t] = k2;
    __syncthreads();

    float he = eb1[t];
    for (int i = 0; i < 64; ++i) he = fmaf(qv[i], eW1[i * 64 + t], he);
    for (int i = 0; i < 64; ++i) he = fmaf(kv[i], eW1[(64 + i) * 64 + t], he);
    he = fmaxf(he, 0.0f);

    float part = he * eW2[t];
    for (int o = 32; o > 0; o >>= 1) part += __shfl_down(part, o);

    if (t == 0) {
        float r;
        if (l == 0) {
            r = 0.0f;                   // logits[:,0] = -1e9 -> sigmoid -> 0
        } else {
            float logit = part + eb2[0];
            r = 1.0f / (1.0f + expf(-logit));
            r = fminf(fmaxf(r, 0.0f), 1.0f);
        }
        out[bl] = r;
    }
}

extern "C" void kernel_launch(void* const* d_in, const int* in_sizes, int n_in,
                              void* d_out, int out_size, void* d_ws, size_t ws_size,
                              hipStream_t stream) {
    const float* psm  = (const float*)d_in[0];
    const float* req  = (const float*)d_in[1];
    const float* naff = (const float*)d_in[2];
    const float* qW1 = (const float*)d_in[4];
    const float* qb1 = (const float*)d_in[5];
    const float* qW2 = (const float*)d_in[6];
    const float* qb2 = (const float*)d_in[7];
    const float* kW1 = (const float*)d_in[8];
    const float* kb1 = (const float*)d_in[9];
    const float* kW2 = (const float*)d_in[10];
    const float* kb2 = (const float*)d_in[11];
    const float* eW1 = (const float*)d_in[12];
    const float* eb1 = (const float*)d_in[13];
    const float* eW2 = (const float*)d_in[14];
    const float* eb2 = (const float*)d_in[15];
    float* out = (float*)d_out;
    float* ws  = (float*)d_ws;

    if (ws_size >= PAIR_OFF_B + PAIR_BYTES) {
        __half2* pairs = (__half2*)((char*)d_ws + PAIR_OFF_B);
        hipLaunchKernelGGL(conf_kernel, dim3(144, NBL), dim3(256), 0, stream,
                           psm, pairs, ws);
        hipLaunchKernelGGL(overlap_kernel, dim3(144 * NBL), dim3(256), 0, stream,
                           req, naff, pairs, ws);
    } else {
        hipLaunchKernelGGL(heavy_kernel, dim3(144 * NBL), dim3(256), 0, stream,
                           psm, req, naff, ws);
    }

    hipLaunchKernelGGL(mlp_kernel, dim3(NBL), dim3(64), 0, stream,
                       ws, naff,
                       qW1, qb1, qW2, qb2, kW1, kb1, kW2, kb2,
                       eW1, eb1, eW2, eb2, out);
}

// Round 7
// 305.314 us; speedup vs baseline: 1.4888x; 1.0108x over previous
//
#include <hip/hip_runtime.h>
#include <math.h>

// Problem constants (fixed by reference): B=16, L=8, A_CH=2, H=W=384, HID=64
#define HWDIM 384
#define PPX   (HWDIM * HWDIM)   // 147456 px per image
#define NBL   128               // B*L
#define NB    16
#define NPART 576               // 144 blocks * 4 waves per image

// ws layout (floats):
//   [1024,   +73728)   partA (conf partials,    128 * 576)
//   [74752,  +73728)   partO (overlap partials, 128 * 576)
//   [148480, +9216)    partD (demand partials,   16 * 576)
// byte 1048576: conf PAIR cache, uchar2 per px = (q[x], q[x+1]), q=conf*255; 37.75 MB
#define PART_A_OFF  1024
#define PART_O_OFF  74752
#define PART_D_OFF  148480
#define PAIR_OFF_B  1048576
#define PAIR_BYTES  ((size_t)NBL * PPX * 2)

__device__ __forceinline__ float fast_sigmoid(float x) {
    return 1.0f / (1.0f + __expf(-x));
}

// force a block-uniform float into an SGPR
__device__ __forceinline__ float uload(const float* p) {
    union { float f; int i; } u;
    u.f = *p;
    u.i = __builtin_amdgcn_readfirstlane(u.i);
    return u.f;
}

// ---- Pass 1: conf = sigmoid(max(ch0,ch1)) -> u8 PAIR cache + partials ------
// 1D grid 18432 = 128 img * 144 blk, XCD-swizzled (same mapping as overlap so
// an image's pairs land in the L2 of the XCD that will gather them).
__global__ __launch_bounds__(256) void conf_kernel(
    const float* __restrict__ psm, unsigned short* __restrict__ pairs,
    float* __restrict__ ws)
{
    const int flat = blockIdx.x;
    const int xcd  = flat & 7;
    const int s    = flat >> 3;
    const int img_in_xcd = s / 144;
    const int blk  = s - img_in_xcd * 144;
    const int bl   = (xcd << 4) | img_in_xcd;
    const int t = threadIdx.x;

    const float* img0 = psm + (size_t)bl * (2 * PPX);
    const int p0 = blk * 1024 + t * 4;

    float4 c0 = *(const float4*)(img0 + p0);
    float4 c1 = *(const float4*)(img0 + PPX + p0);

    float v0 = fast_sigmoid(fmaxf(c0.x, c1.x));
    float v1 = fast_sigmoid(fmaxf(c0.y, c1.y));
    float v2 = fast_sigmoid(fmaxf(c0.z, c1.z));
    float v3 = fast_sigmoid(fmaxf(c0.w, c1.w));

    // neighbor conf (px p0+4) = next lane's v0; lane 63 recomputes directly
    const int lane = t & 63;
    float vn = __shfl(v0, (lane + 1) & 63);
    if (lane == 63) {
        const int pn = p0 + 4;
        float a = 0.0f;
        if (pn < PPX) a = fast_sigmoid(fmaxf(img0[pn], img0[pn + PPX]));
        vn = a;  // consumed only when x<383; junk masked at gather time
    }

    // quantize to u8 (v in (0,1) -> q in [0,255])
    unsigned q0 = (unsigned)(v0 * 255.0f + 0.5f);
    unsigned q1 = (unsigned)(v1 * 255.0f + 0.5f);
    unsigned q2 = (unsigned)(v2 * 255.0f + 0.5f);
    unsigned q3 = (unsigned)(v3 * 255.0f + 0.5f);
    unsigned qn = (unsigned)(vn * 255.0f + 0.5f);

    // pairs for px p0..p0+3: (q0,q1)(q1,q2)(q2,q3)(q3,qn) -> 8 bytes
    uint2 st;
    st.x = q0 | (q1 << 8) | (q1 << 16) | (q2 << 24);
    st.y = q2 | (q3 << 8) | (q3 << 16) | (qn << 24);
    *(uint2*)(pairs + (size_t)bl * PPX + p0) = st;

    float sum = (v0 + v1) + (v2 + v3);
    for (int o = 32; o > 0; o >>= 1) sum += __shfl_down(sum, o);
    if (lane == 0)
        ws[PART_A_OFF + bl * NPART + blk * 4 + (t >> 6)] = sum;
}

// ---- Pass 2: warp-overlap + demand. Wave-contiguous px, ushort gathers. ----
__global__ __launch_bounds__(256) void overlap_kernel(
    const float* __restrict__ req, const float* __restrict__ naff,
    const unsigned short* __restrict__ pairs, float* __restrict__ ws)
{
    const int flat = blockIdx.x;
    const int xcd  = flat & 7;
    const int s    = flat >> 3;            // 0..2303
    const int img_in_xcd = s / 144;        // 0..15
    const int blk  = s - img_in_xcd * 144; // 0..143
    const int bl   = (xcd << 4) | img_in_xcd;
    const int b = bl >> 3;
    const int l = bl & 7;
    const int t = threadIdx.x;

    const float* di_img = req + (size_t)(b * 8) * PPX;
    const unsigned short* pimg = pairs + (size_t)bl * PPX;

    const int ab = (b * 64 + l) * 6;       // norm_affine[b,0,l]
    const float a00 = uload(naff + ab + 0), a01 = uload(naff + ab + 1);
    const float a02 = uload(naff + ab + 2), a10 = uload(naff + ab + 3);
    const float a11 = uload(naff + ab + 4), a12 = uload(naff + ab + 5);

    const float step  = 2.0f / (float)(HWDIM - 1);
    const float half_ = 0.5f * (float)(HWDIM - 1);

    float acc = 0.0f, sdi = 0.0f;

    #pragma unroll
    for (int j = 0; j < 4; ++j) {
        const int p = blk * 1024 + j * 256 + t;   // lane-consecutive px
        const float di = di_img[p];
        sdi += di;

        const int y = p / HWDIM;
        const int x = p - y * HWDIM;
        const float gxv = fmaf((float)x, step, -1.0f);
        const float gyv = fmaf((float)y, step, -1.0f);
        float sx = a00 * gxv + a01 * gyv + a02;
        float sy = a10 * gxv + a11 * gyv + a12;
        float pxf = (sx + 1.0f) * half_;
        float pyf = (sy + 1.0f) * half_;
        float x0f = floorf(pxf), y0f = floorf(pyf);
        float wx = pxf - x0f, wy = pyf - y0f;
        int x0 = (int)x0f, y0 = (int)y0f;

        const bool vx0 = (unsigned)x0 < (unsigned)HWDIM;
        const bool vx1 = (unsigned)(x0 + 1) < (unsigned)HWDIM;
        const bool vy0 = (unsigned)y0 < (unsigned)HWDIM;
        const bool vy1 = (unsigned)(y0 + 1) < (unsigned)HWDIM;
        const int xc  = min(max(x0, 0), HWDIM - 1);
        const int yc0 = min(max(y0, 0), HWDIM - 1);
        const int yc1 = min(max(y0 + 1, 0), HWDIM - 1);

        const unsigned u0 = pimg[yc0 * HWDIM + xc];   // (q[xc], q[xc+1])
        const unsigned u1 = pimg[yc1 * HWDIM + xc];
        const float r0x = (float)(u0 & 0xffu), r0y = (float)(u0 >> 8);
        const float r1x = (float)(u1 & 0xffu), r1y = (float)(u1 >> 8);

        float v00, v01, v10, v11;
        if (vx0) {
            v00 = r0x; v01 = vx1 ? r0y : 0.0f;
            v10 = r1x; v11 = vx1 ? r1y : 0.0f;
        } else {                     // x0 == -1: conf[x0]=0, conf[x0+1]=q[0]
            v00 = 0.0f; v01 = vx1 ? r0x : 0.0f;
            v10 = 0.0f; v11 = vx1 ? r1x : 0.0f;
        }
        if (!vy0) { v00 = 0.0f; v01 = 0.0f; }
        if (!vy1) { v10 = 0.0f; v11 = 0.0f; }

        float top = v00 + wx * (v01 - v00);
        float bot = v10 + wx * (v11 - v10);
        acc = fmaf(di, top + wy * (bot - top), acc);
    }

    for (int o = 32; o > 0; o >>= 1) {
        acc += __shfl_down(acc, o);
        sdi += __shfl_down(sdi, o);
    }
    if ((t & 63) == 0) {
        const int pi = blk * 4 + (t >> 6);
        ws[PART_O_OFF + bl * NPART + pi] = acc * (1.0f / 255.0f);
        if (l == 0) ws[PART_D_OFF + b * NPART + pi] = sdi;
    }
}

// ---- Fallback fused single pass (if ws too small for pair cache) -----------
__device__ __forceinline__ float conf_sample(const float* __restrict__ img0,
                                             int yi, int xi) {
    bool valid = ((unsigned)xi < HWDIM) && ((unsigned)yi < HWDIM);
    int yc = min(max(yi, 0), HWDIM - 1);
    int xc = min(max(xi, 0), HWDIM - 1);
    int off = yc * HWDIM + xc;
    return valid ? fast_sigmoid(fmaxf(img0[off], img0[off + PPX])) : 0.0f;
}

__global__ __launch_bounds__(256) void heavy_kernel(
    const float* __restrict__ psm, const float* __restrict__ req,
    const float* __restrict__ naff, float* __restrict__ ws)
{
    const int flat = blockIdx.x;
    const int xcd  = flat & 7;
    const int s    = flat >> 3;
    const int img_in_xcd = s / 144;
    const int blk  = s - img_in_xcd * 144;
    const int bl   = (xcd << 4) | img_in_xcd;
    const int b = bl >> 3;
    const int l = bl & 7;
    const int t = threadIdx.x;

    const float* img0   = psm + (size_t)bl * (2 * PPX);
    const float* di_img = req + (size_t)(b * 8) * PPX;
    const int ab = (b * 64 + l) * 6;
    const float a00 = uload(naff + ab + 0), a01 = uload(naff + ab + 1);
    const float a02 = uload(naff + ab + 2), a10 = uload(naff + ab + 3);
    const float a11 = uload(naff + ab + 4), a12 = uload(naff + ab + 5);

    const int p0 = blk * 1024 + t * 4;
    const float step  = 2.0f / (float)(HWDIM - 1);
    const float half_ = 0.5f * (float)(HWDIM - 1);
    const int y = p0 / HWDIM;
    const int x = p0 - y * HWDIM;
    const float gyv = fmaf((float)y, step, -1.0f);

    float4 c0  = *(const float4*)(img0 + p0);
    float4 c1  = *(const float4*)(img0 + PPX + p0);
    float4 di4 = *(const float4*)(di_img + p0);

    float s_conf = 0.0f, s_ov = 0.0f;
    float s_di = (di4.x + di4.y) + (di4.z + di4.w);

    #pragma unroll
    for (int j = 0; j < 4; ++j) {
        s_conf += fast_sigmoid(fmaxf((&c0.x)[j], (&c1.x)[j]));
        const float gxv = fmaf((float)(x + j), step, -1.0f);
        float sx = a00 * gxv + a01 * gyv + a02;
        float sy = a10 * gxv + a11 * gyv + a12;
        float pxf = (sx + 1.0f) * half_;
        float pyf = (sy + 1.0f) * half_;
        float x0f = floorf(pxf), y0f = floorf(pyf);
        float wx = pxf - x0f, wy = pyf - y0f;
        int x0 = (int)x0f, y0 = (int)y0f;
        float v00 = conf_sample(img0, y0,     x0);
        float v01 = conf_sample(img0, y0,     x0 + 1);
        float v10 = conf_sample(img0, y0 + 1, x0);
        float v11 = conf_sample(img0, y0 + 1, x0 + 1);
        float top = v00 + wx * (v01 - v00);
        float bot = v10 + wx * (v11 - v10);
        s_ov = fmaf((&di4.x)[j], top + wy * (bot - top), s_ov);
    }

    for (int o = 32; o > 0; o >>= 1) {
        s_conf += __shfl_down(s_conf, o);
        s_ov   += __shfl_down(s_ov,   o);
        s_di   += __shfl_down(s_di,   o);
    }
    if ((t & 63) == 0) {
        const int pi = blk * 4 + (t >> 6);
        ws[PART_A_OFF + bl * NPART + pi] = s_conf;
        ws[PART_O_OFF + bl * NPART + pi] = s_ov;
        if (l == 0) ws[PART_D_OFF + b * NPART + pi] = s_di;
    }
}

// ---- MLP head, one wave per (b,l); reduces its own partials inline ---------
__global__ __launch_bounds__(64) void mlp_kernel(
    const float* __restrict__ ws, const float* __restrict__ naff,
    const float* __restrict__ qW1, const float* __restrict__ qb1,
    const float* __restrict__ qW2, const float* __restrict__ qb2,
    const float* __restrict__ kW1, const float* __restrict__ kb1,
    const float* __restrict__ kW2, const float* __restrict__ kb2,
    const float* __restrict__ eW1, const float* __restrict__ eb1,
    const float* __restrict__ eW2, const float* __restrict__ eb2,
    float* __restrict__ out)
{
    const int bl = blockIdx.x;
    const int b = bl >> 3;
    const int l = bl & 7;
    const int t = threadIdx.x;
    const float invP = 1.0f / (float)PPX;

    const float* pa  = ws + PART_A_OFF + bl * NPART;
    const float* pa0 = ws + PART_A_OFF + (b * 8) * NPART;
    const float* po  = ws + PART_O_OFF + bl * NPART;
    const float* pd  = ws + PART_D_OFF + b * NPART;
    float sA = 0.0f, sA0 = 0.0f, sO = 0.0f, sD = 0.0f;
    for (int k = t; k < NPART; k += 64) {
        sA += pa[k]; sA0 += pa0[k]; sO += po[k]; sD += pd[k];
    }
    for (int o = 32; o > 0; o >>= 1) {
        sA  += __shfl_xor(sA,  o);
        sA0 += __shfl_xor(sA0, o);
        sO  += __shfl_xor(sO,  o);
        sD  += __shfl_xor(sD,  o);
    }

    const float demand = sD * invP;
    const float mc0    = sA0 * invP;
    const float mc     = sA * invP;
    const float ov     = sO * invP;

    const int abase = (b * 64 + l) * 6;
    const float dx = naff[abase + 2];
    const float dy = naff[abase + 5];
    const float dist = sqrtf(dx * dx + dy * dy);

    const int dbase  = (b * 64 + 9 * l) * 6;   // norm_affine[b,l,l]
    const int dbase0 = (b * 64) * 6;           // norm_affine[b,0,0]
    const float yawl = atan2f(naff[dbase + 3],  naff[dbase + 0]);
    const float yaw0 = atan2f(naff[dbase0 + 3], naff[dbase0 + 0]);
    const float tt = yaw0 - yawl;       // cos/sin(atan2(sin t,cos t))==cos/sin(t)
    const float cosd = cosf(tt), sind = sinf(tt);

    const float ego[8] = {mc0, demand, 0.0f, 0.0f, 1.0f, 0.0f, 0.0f, demand};
    const float fj[8]  = {mc, ov, dx, dy, cosd, sind, dist, demand};

    __shared__ float sh[64];
    __shared__ float qv[64];
    __shared__ float kv[64];

    float h = qb1[t];
    for (int i = 0; i < 8; ++i) h = fmaf(ego[i], qW1[i * 64 + t], h);
    sh[t] = fmaxf(h, 0.0f);
    __syncthreads();
    float q2 = qb2[t];
    for (int i = 0; i < 64; ++i) q2 = fmaf(sh[i], qW2[i * 64 + t], q2);
    qv[t] = q2;
    __syncthreads();

    float hk = kb1[t];
    for (int i = 0; i < 8; ++i) hk = fmaf(fj[i], kW1[i * 64 + t], hk);
    sh[t] = fmaxf(hk, 0.0f);
    __syncthreads();
    float k2 = kb2[t];
    for (int i = 0; i < 64; ++i) k2 = fmaf(sh[i], kW2[i * 64 + t], k2);
    kv[t] = k2;
    __syncthreads();

    float he = eb1[t];
    for (int i = 0; i < 64; ++i) he = fmaf(qv[i], eW1[i * 64 + t], he);
    for (int i = 0; i < 64; ++i) he = fmaf(kv[i], eW1[(64 + i) * 64 + t], he);
    he = fmaxf(he, 0.0f);

    float part = he * eW2[t];
    for (int o = 32; o > 0; o >>= 1) part += __shfl_down(part, o);

    if (t == 0) {
        float r;
        if (l == 0) {
            r = 0.0f;                   // logits[:,0] = -1e9 -> sigmoid -> 0
        } else {
            float logit = part + eb2[0];
            r = 1.0f / (1.0f + expf(-logit));
            r = fminf(fmaxf(r, 0.0f), 1.0f);
        }
        out[bl] = r;
    }
}

extern "C" void kernel_launch(void* const* d_in, const int* in_sizes, int n_in,
                              void* d_out, int out_size, void* d_ws, size_t ws_size,
                              hipStream_t stream) {
    const float* psm  = (const float*)d_in[0];
    const float* req  = (const float*)d_in[1];
    const float* naff = (const float*)d_in[2];
    const float* qW1 = (const float*)d_in[4];
    const float* qb1 = (const float*)d_in[5];
    const float* qW2 = (const float*)d_in[6];
    const float* qb2 = (const float*)d_in[7];
    const float* kW1 = (const float*)d_in[8];
    const float* kb1 = (const float*)d_in[9];
    const float* kW2 = (const float*)d_in[10];
    const float* kb2 = (const float*)d_in[11];
    const float* eW1 = (const float*)d_in[12];
    const float* eb1 = (const float*)d_in[13];
    const float* eW2 = (const float*)d_in[14];
    const float* eb2 = (const float*)d_in[15];
    float* out = (float*)d_out;
    float* ws  = (float*)d_ws;

    if (ws_size >= PAIR_OFF_B + PAIR_BYTES) {
        unsigned short* pairs = (unsigned short*)((char*)d_ws + PAIR_OFF_B);
        hipLaunchKernelGGL(conf_kernel, dim3(144 * NBL), dim3(256), 0, stream,
                           psm, pairs, ws);
        hipLaunchKernelGGL(overlap_kernel, dim3(144 * NBL), dim3(256), 0, stream,
                           req, naff, pairs, ws);
    } else {
        hipLaunchKernelGGL(heavy_kernel, dim3(144 * NBL), dim3(256), 0, stream,
                           psm, req, naff, ws);
    }

    hipLaunchKernelGGL(mlp_kernel, dim3(NBL), dim3(64), 0, stream,
                       ws, naff,
                       qW1, qb1, qW2, qb2, kW1, kb1, kW2, kb2,
                       eW1, eb1, eW2, eb2, out);
}